// Round 11
// baseline (276.347 us; speedup 1.0000x reference)
//
#include <hip/hip_runtime.h>
#include <hip/hip_bf16.h>

typedef __attribute__((ext_vector_type(8))) short short8;
typedef __attribute__((ext_vector_type(4))) float floatx4;

#define B_    4
#define S_    2048
#define EMB_  1024
#define NH_   16
#define HD_   64

#if __has_builtin(__builtin_amdgcn_exp2f)
#define EXP2F(x) __builtin_amdgcn_exp2f(x)
#else
#define EXP2F(x) exp2f(x)
#endif

__device__ __forceinline__ void async_cp16(const void* g, void* l) {
  __builtin_amdgcn_global_load_lds(
      (const __attribute__((address_space(1))) unsigned int*)g,
      (__attribute__((address_space(3))) unsigned int*)l, 16, 0, 0);
}

__device__ __forceinline__ ushort4 cvt4(const float4 f) {
  __bf16 t[4] = {(__bf16)f.x, (__bf16)f.y, (__bf16)f.z, (__bf16)f.w};
  return *(const ushort4*)t;
}

// pack two fp32x4 into one bf16x8 fragment: [a0..a3, b0..b3]
__device__ __forceinline__ short8 pack8(const float4 a, const float4 b) {
  union { short8 s; ushort4 u[2]; } r;
  r.u[0] = cvt4(a);
  r.u[1] = cvt4(b);
  return r.s;
}

// One-shot fp32 -> bf16 conversion of x, Wq|Wk|Wv (stacked into Wcat), Wo,
// plus fp32 bias packing bq|bk|bv -> bcat. 4 elems/thread.
__global__ __launch_bounds__(256)
void cvt_kernel(const float* __restrict__ x,
                const float* __restrict__ wq, const float* __restrict__ wk,
                const float* __restrict__ wv, const float* __restrict__ wo,
                const float* __restrict__ bq, const float* __restrict__ bk,
                const float* __restrict__ bv,
                __bf16* __restrict__ xb, __bf16* __restrict__ Wcat,
                __bf16* __restrict__ Wob, float* __restrict__ bcat)
{
  const int NX4 = 2097152;   // 8388608/4
  const int NW4 = 262144;    // 1048576/4
  int g = blockIdx.x * 256 + threadIdx.x;
  if (g < NX4) {
    *(ushort4*)(xb + (size_t)g * 4) = cvt4(*(const float4*)(x + (size_t)g * 4));
    return;
  }
  g -= NX4;
  if (g < 3 * NW4) {   // Wcat = [Wq; Wk; Wv] row-stacked
    const float* src = (g < NW4) ? wq : (g < 2 * NW4) ? wk : wv;
    const int gg = (g < NW4) ? g : (g < 2 * NW4) ? g - NW4 : g - 2 * NW4;
    *(ushort4*)(Wcat + (size_t)g * 4) = cvt4(*(const float4*)(src + (size_t)gg * 4));
    return;
  }
  g -= 3 * NW4;
  if (g < NW4) {
    *(ushort4*)(Wob + (size_t)g * 4) = cvt4(*(const float4*)(wo + (size_t)g * 4));
    return;
  }
  g -= NW4;
  if (g < 768) {       // bcat = [bq; bk; bv] fp32
    const float* src = (g < 256) ? bq : (g < 512) ? bk : bv;
    *(float4*)(bcat + (size_t)g * 4) = *(const float4*)(src + (size_t)(g & 255) * 4);
  }
}

// Fused QKV: C[8192,3072] = xb @ Wcat^T + bcat, all bf16, global_load_lds staging.
// n<1024 -> Q (scaled by SCL*log2e) BHSD; n<2048 -> K BHSD; else -> V^T BHDS.
// BANK-CONFLICT FIX (round 11): rows are 64 B so the old ds_read_b128 at
// row*64B + quad*16B was an 8-way conflict (16 l15-lanes on 4 slots).
// Swizzle: stage global col chunk (tid&3)^((tid>>3)&3) into linear LDS slot
// tid&3 (global addr is per-lane, LDS dest stays linear -- rule 21), read
// slot quad ^ ((l15>>1)&3). Banks spread over 8 slots -> 2-way (free).
__global__ __launch_bounds__(256)
void gemm_qkv_kernel(const __bf16* __restrict__ A, const __bf16* __restrict__ W,
                     const float* __restrict__ bcat,
                     __bf16* __restrict__ Qb, __bf16* __restrict__ Kb,
                     __bf16* __restrict__ Vb)
{
  __shared__ __attribute__((aligned(16))) __bf16 As[128 * 32];
  __shared__ __attribute__((aligned(16))) __bf16 Ws[128 * 32];
  const int tid  = threadIdx.x;
  const int wave = tid >> 6, lane = tid & 63;
  const int l15  = lane & 15, quad = lane >> 4;
  const int wm   = wave >> 1, wn = wave & 1;
  const int bm   = blockIdx.y * 128;
  const int bn   = blockIdx.x * 128;        // 0..2944
  const int widx = bn >> 10;                // 0=Q 1=K 2=V (block-uniform)
  const float QS = 0.180336880f;            // (1/sqrt(64)) * log2(e)

  floatx4 acc[4][4];
#pragma unroll
  for (int i = 0; i < 4; ++i)
#pragma unroll
    for (int j = 0; j < 4; ++j) acc[i][j] = (floatx4){0.f, 0.f, 0.f, 0.f};

  const int srow = tid >> 2;          // 0..63
  const int gcol = (((tid & 3) ^ ((tid >> 3) & 3)) << 3);   // swizzled global col
  const int xsw  = (l15 >> 1) & 3;                          // read-side swizzle
  const __bf16* Ag = A + (size_t)(bm + srow) * 1024 + gcol;
  const __bf16* Wg = W + (size_t)(bn + srow) * 1024 + gcol;
  __bf16* AsD = As + tid * 8;
  __bf16* WsD = Ws + tid * 8;

  for (int k0 = 0; k0 < 1024; k0 += 32) {
    __syncthreads();
    async_cp16(Ag + k0,             AsD);
    async_cp16(Ag + k0 + 64 * 1024, AsD + 2048);
    async_cp16(Wg + k0,             WsD);
    async_cp16(Wg + k0 + 64 * 1024, WsD + 2048);
    __syncthreads();
    short8 af[4], wf[4];
#pragma unroll
    for (int mi = 0; mi < 4; ++mi)
      af[mi] = *(const short8*)(As + ((wm * 64 + mi * 16 + l15) << 5) + ((quad ^ xsw) << 3));
#pragma unroll
    for (int ni = 0; ni < 4; ++ni)
      wf[ni] = *(const short8*)(Ws + ((wn * 64 + ni * 16 + l15) << 5) + ((quad ^ xsw) << 3));
#pragma unroll
    for (int mi = 0; mi < 4; ++mi)
#pragma unroll
      for (int ni = 0; ni < 4; ++ni)
        acc[mi][ni] = __builtin_amdgcn_mfma_f32_16x16x32_bf16(af[mi], wf[ni], acc[mi][ni], 0, 0, 0);
  }

#pragma unroll
  for (int ni = 0; ni < 4; ++ni) {
    const int n  = bn + wn * 64 + ni * 16 + l15;
    const float bvb = bcat[n];
    const int np = n & 1023;
    const int h = np >> 6, d = np & 63;
#pragma unroll
    for (int mi = 0; mi < 4; ++mi) {
      const int m0 = bm + wm * 64 + mi * 16 + quad * 4;
      const int b = m0 >> 11, s0 = m0 & 2047;
      floatx4 v = acc[mi][ni];
      if (widx == 0) {
        const size_t base = (size_t)(b * 16 + h) * (S_ * 64) + d;
#pragma unroll
        for (int r = 0; r < 4; ++r)
          Qb[base + (size_t)(s0 + r) * 64] = (__bf16)((v[r] + bvb) * QS);
      } else if (widx == 1) {
        const size_t base = (size_t)(b * 16 + h) * (S_ * 64) + d;
#pragma unroll
        for (int r = 0; r < 4; ++r)
          Kb[base + (size_t)(s0 + r) * 64] = (__bf16)(v[r] + bvb);
      } else {
        const size_t base = ((size_t)(b * 16 + h) * 64 + d) * S_ + s0;
        union { ushort4 u4; unsigned short u[4]; } pk;
#pragma unroll
        for (int r = 0; r < 4; ++r) {
          __bf16 hv = (__bf16)(v[r] + bvb);
          pk.u[r] = *(unsigned short*)&hv;
        }
        *(ushort4*)(Vb + base) = pk.u4;    // 8B aligned: s0 % 4 == 0
      }
    }
  }
}

// Online-softmax update for one 16-row q-group (lane owns q=l15). With the
// PERMUTED K-row mapping, lane (l15,quad) holds s[ni][r] = S at
// kv = (ni&1)*32 + quad*8 + (ni>>1)*4 + r  -- so the PV B-fragment is a
// LANE-LOCAL repack: pf0 = [p0, p2] (kv = quad*8+0..7), pf1 = [p1, p3]
// (kv = 32+quad*8+0..7). No Ps LDS buffer, no shfl exchange, no lgkm fence.
// T13 defer-max; tmax cross-quad reduced (all 4 quads of a q-row together
// cover the full 64 kv).
__device__ __forceinline__ void softmax_update_pf(
    floatx4* s, float& mrun, float& lsum, floatx4* oacc,
    short8& pf0, short8& pf1)
{
  float t0 = fmaxf(fmaxf(s[0][0], s[0][1]), fmaxf(s[0][2], s[0][3]));
  float t1 = fmaxf(fmaxf(s[1][0], s[1][1]), fmaxf(s[1][2], s[1][3]));
  float t2 = fmaxf(fmaxf(s[2][0], s[2][1]), fmaxf(s[2][2], s[2][3]));
  float t3 = fmaxf(fmaxf(s[3][0], s[3][1]), fmaxf(s[3][2], s[3][3]));
  float tmax = fmaxf(fmaxf(t0, t1), fmaxf(t2, t3));
  tmax = fmaxf(tmax, __shfl_xor(tmax, 16));
  tmax = fmaxf(tmax, __shfl_xor(tmax, 32));

  const float mold = mrun;
  if (!__all(tmax <= mold + 8.0f)) {      // slow path: rescale
    const float mnew = fmaxf(mold, tmax);
    const float alpha = EXP2F(mold - mnew);
#pragma unroll
    for (int ni = 0; ni < 4; ++ni)
#pragma unroll
      for (int r = 0; r < 4; ++r) oacc[ni][r] *= alpha;
    lsum *= alpha;
    mrun = mnew;
  }
  const float m = mrun;

  float4 p0, p1, p2, p3;
  p0.x = EXP2F(s[0][0] - m); p0.y = EXP2F(s[0][1] - m);
  p0.z = EXP2F(s[0][2] - m); p0.w = EXP2F(s[0][3] - m);
  p1.x = EXP2F(s[1][0] - m); p1.y = EXP2F(s[1][1] - m);
  p1.z = EXP2F(s[1][2] - m); p1.w = EXP2F(s[1][3] - m);
  p2.x = EXP2F(s[2][0] - m); p2.y = EXP2F(s[2][1] - m);
  p2.z = EXP2F(s[2][2] - m); p2.w = EXP2F(s[2][3] - m);
  p3.x = EXP2F(s[3][0] - m); p3.y = EXP2F(s[3][1] - m);
  p3.z = EXP2F(s[3][2] - m); p3.w = EXP2F(s[3][3] - m);

  lsum += ((p0.x + p0.y) + (p0.z + p0.w)) + ((p1.x + p1.y) + (p1.z + p1.w))
        + ((p2.x + p2.y) + (p2.z + p2.w)) + ((p3.x + p3.y) + (p3.z + p3.w));

  pf0 = pack8(p0, p2);    // kv = quad*8 + 0..7       (PV call kk=0)
  pf1 = pack8(p1, p3);    // kv = 32 + quad*8 + 0..7  (PV call kk=1)
}

// Flash attention, causal, exp2-domain (Q pre-scaled by SCL*log2e).
// Round-10 structure + Ks PHYSICAL ROW PERMUTATION (round 11): instead of
// reading permuted rows f(ni,l15) from a linearly-stored Ks (stride 80 ->
// 4-way bank conflict), K row kv is STORED at phys row p = 16*ni + m
// (p(f(ni,m)) = ni*16+m, verified algebraically), so the fragment read is
// linear Ks[(ni*16+l15)*72 + ...] at stride 72 -- same conflict-free
// pattern as Vs (2-way, free). prow = 32*((srow>>2)&1) + 4*((srow>>3)&3)
// + (srow&3); row srow+32 lands at prow+16. kv semantics (mask formula,
// P->PV lane-local repack) unchanged from round 10.
// Block = 4 waves = 128 q-rows (two 16-row groups per wave sharing K/V
// fragment reads); grid (8, 64); serial pairing {qt, 15-qt}; 2 blocks/CU.
// KVBLK=64, 16x16 MFMA, SWAPPED OPERANDS (S^T = mfma(K,Q), lane owns
// q-row = l15), lane-local softmax, T13 defer-max, T14 prefetch in NAMED
// scalars (uint4 arrays spill -- rounds 4/5). Output IN-PLACE over Q.
// LDS 18.4 KB.
__global__ __launch_bounds__(256, 2)
void attn_kernel(__bf16* __restrict__ Q, const __bf16* __restrict__ K,
                 const __bf16* __restrict__ Vt)
{
  __shared__ __attribute__((aligned(16))) __bf16 Ks[64 * 72];      // [phys kv][d]
  __shared__ __attribute__((aligned(16))) __bf16 Vs[64 * 72];      // [d][kv]

  const int tid  = threadIdx.x;
  const int wave = tid >> 6, lane = tid & 63;
  const int l15  = lane & 15, quad = lane >> 4;
  const int qtA  = blockIdx.x, bh = blockIdx.y;   // qtA in 0..7
  const size_t hb = (size_t)bh * (S_ * 64);
  const float MASKV = -1.0e30f;

  const int srow = tid >> 3;          // 0..31
  const int scol = (tid & 7) << 3;    // 0,8,...,56
  // physical row for K permutation: row srow -> prow, row srow+32 -> prow+16
  const int prow = ((srow >> 2) & 1) * 32 + ((srow >> 3) & 3) * 4 + (srow & 3);

  for (int qsel = 0; qsel < 2; ++qsel) {
    const int qt = qsel ? (15 - qtA) : qtA;   // 128-row q-tile index
    const int qw = qt * 128 + wave * 32;      // wave's first q row
    const int myqA = qw + l15;                // group A lane q row
    const int myqB = qw + 16 + l15;           // group B lane q row
    const int nsub = 2 * qt + 2;              // 64-kv sub-tiles to stage

    // Q fragments (B-operand view Q^T[c][q=l15]), named scalars
    const __bf16* qpA = Q + hb + (size_t)myqA * 64 + quad * 8;
    const __bf16* qpB = Q + hb + (size_t)myqB * 64 + quad * 8;
    short8 aqA0 = *(const short8*)(qpA);
    short8 aqA1 = *(const short8*)(qpA + 32);
    short8 aqB0 = *(const short8*)(qpB);
    short8 aqB1 = *(const short8*)(qpB + 32);

    floatx4 oaccA[4], oaccB[4];     // O^T: d = ni*16+quad*4+r, q = l15
#pragma unroll
    for (int j = 0; j < 4; ++j) {
      oaccA[j] = (floatx4){0.f, 0.f, 0.f, 0.f};
      oaccB[j] = (floatx4){0.f, 0.f, 0.f, 0.f};
    }
    float lsumA = 0.f, lsumB = 0.f;
    float mrunA = MASKV, mrunB = MASKV;

    // prologue: issue kt=0 tile loads into NAMED scalar regs (T14 issue-early)
    uint4 kreg0, kreg1, vreg0, vreg1;
    {
      const __bf16* kp = K  + hb + (size_t)srow * 64 + scol;
      const __bf16* vp = Vt + hb + (size_t)srow * S_ + scol;
      kreg0 = *(const uint4*)kp;
      kreg1 = *(const uint4*)(kp + 32 * 64);
      vreg0 = *(const uint4*)vp;
      vreg1 = *(const uint4*)(vp + (size_t)32 * S_);
    }

    for (int kt = 0; kt < nsub; ++kt) {
      __syncthreads();                      // all waves done reading prev tile
      *(uint4*)(&Ks[prow * 72 + scol])        = kreg0;   // K row srow
      *(uint4*)(&Ks[(prow + 16) * 72 + scol]) = kreg1;   // K row srow+32
      *(uint4*)(&Vs[srow * 72 + scol])        = vreg0;
      *(uint4*)(&Vs[(srow + 32) * 72 + scol]) = vreg1;
      __syncthreads();                      // tile staged

      if (kt + 1 < nsub) {                  // prefetch next 64-kv tile
        const __bf16* kp = K  + hb + (size_t)((kt + 1) * 64 + srow) * 64 + scol;
        const __bf16* vp = Vt + hb + (size_t)srow * S_ + (kt + 1) * 64 + scol;
        kreg0 = *(const uint4*)kp;
        kreg1 = *(const uint4*)(kp + 32 * 64);
        vreg0 = *(const uint4*)vp;
        vreg1 = *(const uint4*)(vp + (size_t)32 * S_);
      }

      if (kt * 64 <= qw + 31) {             // wave-uniform compute-skip
        // S^T = K Q^T for BOTH groups; bk fragments read ONCE (linear rows,
        // permuted CONTENT: phys row ni*16+l15 holds K row f(ni,l15)).
        floatx4 sA[4], sB[4];
#pragma unroll
        for (int j = 0; j < 4; ++j) {
          sA[j] = (floatx4){0.f, 0.f, 0.f, 0.f};
          sB[j] = (floatx4){0.f, 0.f, 0.f, 0.f};
        }
#pragma unroll
        for (int kk = 0; kk < 2; ++kk) {
          const short8 aqa = kk ? aqA1 : aqA0;
          const short8 aqb = kk ? aqB1 : aqB0;
          short8 bk[4];
#pragma unroll
          for (int ni = 0; ni < 4; ++ni)
            bk[ni] = *(const short8*)(&Ks[(ni * 16 + l15) * 72 + kk * 32 + quad * 8]);
#pragma unroll
          for (int ni = 0; ni < 4; ++ni)
            sA[ni] = __builtin_amdgcn_mfma_f32_16x16x32_bf16(bk[ni], aqa, sA[ni], 0, 0, 0);
#pragma unroll
          for (int ni = 0; ni < 4; ++ni)
            sB[ni] = __builtin_amdgcn_mfma_f32_16x16x32_bf16(bk[ni], aqb, sB[ni], 0, 0, 0);
        }

        // causal masks with kv = kt*64 + (ni&1)*32 + quad*8 + (ni>>1)*4 + r
        const int kb2 = kt * 64 + quad * 8;
        if (kt * 64 + 63 > qw) {            // group A diagonal overlap
#pragma unroll
          for (int ni = 0; ni < 4; ++ni)
#pragma unroll
            for (int r = 0; r < 4; ++r) {
              const int kvg = kb2 + ((ni & 1) << 5) + ((ni >> 1) << 2) + r;
              if (kvg > myqA) sA[ni][r] = MASKV;
            }
        }
        if (kt * 64 + 63 > qw + 16) {       // group B diagonal overlap
#pragma unroll
          for (int ni = 0; ni < 4; ++ni)
#pragma unroll
            for (int r = 0; r < 4; ++r) {
              const int kvg = kb2 + ((ni & 1) << 5) + ((ni >> 1) << 2) + r;
              if (kvg > myqB) sB[ni][r] = MASKV;
            }
        }

        short8 pfA0, pfA1, pfB0, pfB1;
        softmax_update_pf(sA, mrunA, lsumA, oaccA, pfA0, pfA1);
        softmax_update_pf(sB, mrunB, lsumB, oaccB, pfB0, pfB1);

        // O^T += V^T P^T; P fragments are lane-local (no LDS, no fence).
#pragma unroll
        for (int kk = 0; kk < 2; ++kk) {
          short8 bv[4];
#pragma unroll
          for (int ni = 0; ni < 4; ++ni)
            bv[ni] = *(const short8*)(&Vs[(ni * 16 + l15) * 72 + kk * 32 + quad * 8]);
          const short8 pfA = kk ? pfA1 : pfA0;
          const short8 pfB = kk ? pfB1 : pfB0;
#pragma unroll
          for (int ni = 0; ni < 4; ++ni)
            oaccA[ni] = __builtin_amdgcn_mfma_f32_16x16x32_bf16(bv[ni], pfA, oaccA[ni], 0, 0, 0);
#pragma unroll
          for (int ni = 0; ni < 4; ++ni)
            oaccB[ni] = __builtin_amdgcn_mfma_f32_16x16x32_bf16(bv[ni], pfB, oaccB[ni], 0, 0, 0);
        }
      }
    }

    // epilogues: l(q) = sum over 4 quads of lane-local partials
    {
      float l = lsumA;
      l += __shfl_xor(l, 16);
      l += __shfl_xor(l, 32);
      const float inv = 1.0f / fmaxf(l, 1e-20f);
      const size_t rowb = hb + (size_t)myqA * 64;
#pragma unroll
      for (int ni = 0; ni < 4; ++ni) {
        float4 o;
        o.x = oaccA[ni][0] * inv;
        o.y = oaccA[ni][1] * inv;
        o.z = oaccA[ni][2] * inv;
        o.w = oaccA[ni][3] * inv;
        *(ushort4*)(Q + rowb + ni * 16 + quad * 4) = cvt4(o);  // 8B aligned
      }
    }
    {
      float l = lsumB;
      l += __shfl_xor(l, 16);
      l += __shfl_xor(l, 32);
      const float inv = 1.0f / fmaxf(l, 1e-20f);
      const size_t rowb = hb + (size_t)myqB * 64;
#pragma unroll
      for (int ni = 0; ni < 4; ++ni) {
        float4 o;
        o.x = oaccB[ni][0] * inv;
        o.y = oaccB[ni][1] * inv;
        o.z = oaccB[ni][2] * inv;
        o.w = oaccB[ni][3] * inv;
        *(ushort4*)(Q + rowb + ni * 16 + quad * 4) = cvt4(o);  // 8B aligned
      }
    }
  }
}

// Final projection: A = attn output (bf16, BHSD gather), W = Wob bf16,
// bias fp32, out fp32 row-major. global_load_lds staging.
// Same bank-conflict swizzle as gemm_qkv (8-way -> 2-way).
__global__ __launch_bounds__(256)
void gemm_o_kernel(const __bf16* __restrict__ A, const __bf16* __restrict__ W,
                   const float* __restrict__ bias, float* __restrict__ out)
{
  __shared__ __attribute__((aligned(16))) __bf16 As[128 * 32];
  __shared__ __attribute__((aligned(16))) __bf16 Ws[128 * 32];
  const int tid  = threadIdx.x;
  const int wave = tid >> 6, lane = tid & 63;
  const int l15  = lane & 15, quad = lane >> 4;
  const int wm   = wave >> 1, wn = wave & 1;
  const int bm   = blockIdx.y * 128;
  const int bn   = blockIdx.x * 128;

  floatx4 acc[4][4];
#pragma unroll
  for (int i = 0; i < 4; ++i)
#pragma unroll
    for (int j = 0; j < 4; ++j) acc[i][j] = (floatx4){0.f, 0.f, 0.f, 0.f};

  const int srow = tid >> 2;
  const int gcol = (((tid & 3) ^ ((tid >> 3) & 3)) << 3);   // swizzled global col
  const int xsw  = (l15 >> 1) & 3;                          // read-side swizzle
  const __bf16* Wg = W + (size_t)(bn + srow) * 1024 + gcol;
  const int bb = bm >> 11;                 // batch
  const int ss = (bm & 2047) + srow;       // seq
  __bf16* AsD = As + tid * 8;
  __bf16* WsD = Ws + tid * 8;

  for (int k0 = 0; k0 < 1024; k0 += 32) {
    const int c = k0 + gcol, h = c >> 6, dd = c & 63;  // 8-aligned chunks never cross a head
    const __bf16* pa0 = A + (((size_t)(bb * 16 + h) * S_) + ss) * 64 + dd;
    __syncthreads();
    async_cp16(pa0,           AsD);
    async_cp16(pa0 + 64 * 64, AsD + 2048);             // s -> s+64
    async_cp16(Wg + k0,             WsD);
    async_cp16(Wg + k0 + 64 * 1024, WsD + 2048);
    __syncthreads();

    short8 af[4], wf[4];
#pragma unroll
    for (int mi = 0; mi < 4; ++mi)
      af[mi] = *(const short8*)(As + ((wm * 64 + mi * 16 + l15) << 5) + ((quad ^ xsw) << 3));
#pragma unroll
    for (int ni = 0; ni < 4; ++ni)
      wf[ni] = *(const short8*)(Ws + ((wn * 64 + ni * 16 + l15) << 5) + ((quad ^ xsw) << 3));
#pragma unroll
    for (int mi = 0; mi < 4; ++mi)
#pragma unroll
      for (int ni = 0; ni < 4; ++ni)
        acc[mi][ni] = __builtin_amdgcn_mfma_f32_16x16x32_bf16(af[mi], wf[ni], acc[mi][ni], 0, 0, 0);
  }

#pragma unroll
  for (int ni = 0; ni < 4; ++ni) {
    const int n = bn + wn * 64 + ni * 16 + l15;
    const float bvb = bias[n];
#pragma unroll
    for (int mi = 0; mi < 4; ++mi) {
      const int m0 = bm + wm * 64 + mi * 16 + quad * 4;
      floatx4 v = acc[mi][ni];
#pragma unroll
      for (int r = 0; r < 4; ++r)
        out[(size_t)(m0 + r) * 1024 + n] = v[r] + bvb;
    }
  }
}

extern "C" void kernel_launch(void* const* d_in, const int* in_sizes, int n_in,
                              void* d_out, int out_size, void* d_ws, size_t ws_size,
                              hipStream_t stream) {
  const float* x  = (const float*)d_in[0];
  const float* Wq = (const float*)d_in[1];
  const float* bq = (const float*)d_in[2];
  const float* Wk = (const float*)d_in[3];
  const float* bk = (const float*)d_in[4];
  const float* Wv = (const float*)d_in[5];
  const float* bv = (const float*)d_in[6];
  const float* Wo = (const float*)d_in[7];
  const float* bo = (const float*)d_in[8];
  // d_in[9] = causal_mask (int32) — causality implemented analytically, unused.

  const size_t BUF = (size_t)B_ * NH_ * S_ * HD_;   // 8388608 elems
  __bf16* ws   = (__bf16*)d_ws;                     // ws usage: ~42 MB
  __bf16* xb   = ws;                                // 8388608  (16.8 MB)
  __bf16* Wcat = ws + 8388608;                      // 3145728  (6 MB)
  __bf16* Wob  = ws + 11534336;                     // 1048576  (2 MB)
  __bf16* Qb   = ws + 12582912;                     // 8388608  (16.8 MB)
  float*  bcat = (float*)(ws + 20971520);           // 3072 fp32 (12 KB)
  __bf16* Kb   = (__bf16*)d_out;                    // d_out reused as K+V^T
  __bf16* Vb   = (__bf16*)d_out + BUF;              // scratch until attn done

  dim3 blk(256);
  cvt_kernel<<<12291, blk, 0, stream>>>(x, Wq, Wk, Wv, Wo, bq, bk, bv,
                                        xb, Wcat, Wob, bcat);
  gemm_qkv_kernel<<<dim3(24, 64), blk, 0, stream>>>(xb, Wcat, bcat, Qb, Kb, Vb);
  attn_kernel<<<dim3(8, 64), blk, 0, stream>>>(Qb, Kb, Vb);
  gemm_o_kernel<<<dim3(8, 64), blk, 0, stream>>>(Qb, Wob, bo, (float*)d_out);
}

// Round 12
// 267.617 us; speedup vs baseline: 1.0326x; 1.0326x over previous
//
#include <hip/hip_runtime.h>
#include <hip/hip_bf16.h>

typedef __attribute__((ext_vector_type(8))) short short8;
typedef __attribute__((ext_vector_type(4))) float floatx4;

#define B_    4
#define S_    2048
#define EMB_  1024
#define NH_   16
#define HD_   64

#if __has_builtin(__builtin_amdgcn_exp2f)
#define EXP2F(x) __builtin_amdgcn_exp2f(x)
#else
#define EXP2F(x) exp2f(x)
#endif

__device__ __forceinline__ void async_cp16(const void* g, void* l) {
  __builtin_amdgcn_global_load_lds(
      (const __attribute__((address_space(1))) unsigned int*)g,
      (__attribute__((address_space(3))) unsigned int*)l, 16, 0, 0);
}

__device__ __forceinline__ ushort4 cvt4(const float4 f) {
  __bf16 t[4] = {(__bf16)f.x, (__bf16)f.y, (__bf16)f.z, (__bf16)f.w};
  return *(const ushort4*)t;
}

// pack two fp32x4 into one bf16x8 fragment: [a0..a3, b0..b3]
__device__ __forceinline__ short8 pack8(const float4 a, const float4 b) {
  union { short8 s; ushort4 u[2]; } r;
  r.u[0] = cvt4(a);
  r.u[1] = cvt4(b);
  return r.s;
}

// One-shot fp32 -> bf16 conversion of x, Wq|Wk|Wv (stacked into Wcat), Wo,
// plus fp32 bias packing bq|bk|bv -> bcat. 4 elems/thread.
__global__ __launch_bounds__(256)
void cvt_kernel(const float* __restrict__ x,
                const float* __restrict__ wq, const float* __restrict__ wk,
                const float* __restrict__ wv, const float* __restrict__ wo,
                const float* __restrict__ bq, const float* __restrict__ bk,
                const float* __restrict__ bv,
                __bf16* __restrict__ xb, __bf16* __restrict__ Wcat,
                __bf16* __restrict__ Wob, float* __restrict__ bcat)
{
  const int NX4 = 2097152;   // 8388608/4
  const int NW4 = 262144;    // 1048576/4
  int g = blockIdx.x * 256 + threadIdx.x;
  if (g < NX4) {
    *(ushort4*)(xb + (size_t)g * 4) = cvt4(*(const float4*)(x + (size_t)g * 4));
    return;
  }
  g -= NX4;
  if (g < 3 * NW4) {   // Wcat = [Wq; Wk; Wv] row-stacked
    const float* src = (g < NW4) ? wq : (g < 2 * NW4) ? wk : wv;
    const int gg = (g < NW4) ? g : (g < 2 * NW4) ? g - NW4 : g - 2 * NW4;
    *(ushort4*)(Wcat + (size_t)g * 4) = cvt4(*(const float4*)(src + (size_t)gg * 4));
    return;
  }
  g -= 3 * NW4;
  if (g < NW4) {
    *(ushort4*)(Wob + (size_t)g * 4) = cvt4(*(const float4*)(wo + (size_t)g * 4));
    return;
  }
  g -= NW4;
  if (g < 768) {       // bcat = [bq; bk; bv] fp32
    const float* src = (g < 256) ? bq : (g < 512) ? bk : bv;
    *(float4*)(bcat + (size_t)g * 4) = *(const float4*)(src + (size_t)(g & 255) * 4);
  }
}

// Fused QKV: C[8192,3072] = xb @ Wcat^T + bcat, all bf16.
// T3 MINIMUM 2-PHASE (round 12): double-buffered As/Ws; tile k+1's
// global_load_lds issued into the OTHER buffer BEFORE computing tile k, ONE
// barrier per k-step (was: issue -> immediate barrier = full load latency
// exposed every iteration; MfmaUtil 28% + 56% stall). Two k-steps per loop
// iteration with statically-named buf0/buf1. Bank-conflict swizzle (round
// 11, conflicts = 0) kept: swizzled global col + read slot quad^((l15>>1)&3).
__global__ __launch_bounds__(256)
void gemm_qkv_kernel(const __bf16* __restrict__ A, const __bf16* __restrict__ W,
                     const float* __restrict__ bcat,
                     __bf16* __restrict__ Qb, __bf16* __restrict__ Kb,
                     __bf16* __restrict__ Vb)
{
  __shared__ __attribute__((aligned(16))) __bf16 As0[128 * 32];
  __shared__ __attribute__((aligned(16))) __bf16 Ws0[128 * 32];
  __shared__ __attribute__((aligned(16))) __bf16 As1[128 * 32];
  __shared__ __attribute__((aligned(16))) __bf16 Ws1[128 * 32];
  const int tid  = threadIdx.x;
  const int wave = tid >> 6, lane = tid & 63;
  const int l15  = lane & 15, quad = lane >> 4;
  const int wm   = wave >> 1, wn = wave & 1;
  const int bm   = blockIdx.y * 128;
  const int bn   = blockIdx.x * 128;        // 0..2944
  const int widx = bn >> 10;                // 0=Q 1=K 2=V (block-uniform)
  const float QS = 0.180336880f;            // (1/sqrt(64)) * log2(e)

  floatx4 acc[4][4];
#pragma unroll
  for (int i = 0; i < 4; ++i)
#pragma unroll
    for (int j = 0; j < 4; ++j) acc[i][j] = (floatx4){0.f, 0.f, 0.f, 0.f};

  const int srow = tid >> 2;          // 0..63
  const int gcol = (((tid & 3) ^ ((tid >> 3) & 3)) << 3);   // swizzled global col
  const int xsw  = (l15 >> 1) & 3;                          // read-side swizzle
  const __bf16* Ag = A + (size_t)(bm + srow) * 1024 + gcol;
  const __bf16* Wg = W + (size_t)(bn + srow) * 1024 + gcol;
  const int d8 = tid * 8;

  auto stage = [&](__bf16* bA, __bf16* bW, int kk) {
    async_cp16(Ag + kk,             bA + d8);
    async_cp16(Ag + kk + 64 * 1024, bA + d8 + 2048);
    async_cp16(Wg + kk,             bW + d8);
    async_cp16(Wg + kk + 64 * 1024, bW + d8 + 2048);
  };
  auto compute = [&](const __bf16* bA, const __bf16* bW) {
    short8 af[4], wf[4];
#pragma unroll
    for (int mi = 0; mi < 4; ++mi)
      af[mi] = *(const short8*)(bA + ((wm * 64 + mi * 16 + l15) << 5) + ((quad ^ xsw) << 3));
#pragma unroll
    for (int ni = 0; ni < 4; ++ni)
      wf[ni] = *(const short8*)(bW + ((wn * 64 + ni * 16 + l15) << 5) + ((quad ^ xsw) << 3));
#pragma unroll
    for (int mi = 0; mi < 4; ++mi)
#pragma unroll
      for (int ni = 0; ni < 4; ++ni)
        acc[mi][ni] = __builtin_amdgcn_mfma_f32_16x16x32_bf16(af[mi], wf[ni], acc[mi][ni], 0, 0, 0);
  };

  stage(As0, Ws0, 0);
  __syncthreads();                              // buf0 ready
  for (int k0 = 0; k0 < 1024; k0 += 64) {
    stage(As1, Ws1, k0 + 32);                   // DMA k+1 -> buf1 (overlaps)
    compute(As0, Ws0);
    __syncthreads();                            // buf1 ready; buf0 free
    if (k0 + 64 < 1024) stage(As0, Ws0, k0 + 64);
    compute(As1, Ws1);
    __syncthreads();                            // buf0 ready; buf1 free
  }

#pragma unroll
  for (int ni = 0; ni < 4; ++ni) {
    const int n  = bn + wn * 64 + ni * 16 + l15;
    const float bvb = bcat[n];
    const int np = n & 1023;
    const int h = np >> 6, d = np & 63;
#pragma unroll
    for (int mi = 0; mi < 4; ++mi) {
      const int m0 = bm + wm * 64 + mi * 16 + quad * 4;
      const int b = m0 >> 11, s0 = m0 & 2047;
      floatx4 v = acc[mi][ni];
      if (widx == 0) {
        const size_t base = (size_t)(b * 16 + h) * (S_ * 64) + d;
#pragma unroll
        for (int r = 0; r < 4; ++r)
          Qb[base + (size_t)(s0 + r) * 64] = (__bf16)((v[r] + bvb) * QS);
      } else if (widx == 1) {
        const size_t base = (size_t)(b * 16 + h) * (S_ * 64) + d;
#pragma unroll
        for (int r = 0; r < 4; ++r)
          Kb[base + (size_t)(s0 + r) * 64] = (__bf16)(v[r] + bvb);
      } else {
        const size_t base = ((size_t)(b * 16 + h) * 64 + d) * S_ + s0;
        union { ushort4 u4; unsigned short u[4]; } pk;
#pragma unroll
        for (int r = 0; r < 4; ++r) {
          __bf16 hv = (__bf16)(v[r] + bvb);
          pk.u[r] = *(unsigned short*)&hv;
        }
        *(ushort4*)(Vb + base) = pk.u4;    // 8B aligned: s0 % 4 == 0
      }
    }
  }
}

// Online-softmax update for one 16-row q-group (lane owns q=l15). With the
// PERMUTED K-row mapping, lane (l15,quad) holds s[ni][r] = S at
// kv = (ni&1)*32 + quad*8 + (ni>>1)*4 + r  -- so the PV B-fragment is a
// LANE-LOCAL repack: pf0 = [p0, p2] (kv = quad*8+0..7), pf1 = [p1, p3]
// (kv = 32+quad*8+0..7). No Ps LDS buffer, no shfl exchange, no lgkm fence.
// T13 defer-max; tmax cross-quad reduced.
__device__ __forceinline__ void softmax_update_pf(
    floatx4* s, float& mrun, float& lsum, floatx4* oacc,
    short8& pf0, short8& pf1)
{
  float t0 = fmaxf(fmaxf(s[0][0], s[0][1]), fmaxf(s[0][2], s[0][3]));
  float t1 = fmaxf(fmaxf(s[1][0], s[1][1]), fmaxf(s[1][2], s[1][3]));
  float t2 = fmaxf(fmaxf(s[2][0], s[2][1]), fmaxf(s[2][2], s[2][3]));
  float t3 = fmaxf(fmaxf(s[3][0], s[3][1]), fmaxf(s[3][2], s[3][3]));
  float tmax = fmaxf(fmaxf(t0, t1), fmaxf(t2, t3));
  tmax = fmaxf(tmax, __shfl_xor(tmax, 16));
  tmax = fmaxf(tmax, __shfl_xor(tmax, 32));

  const float mold = mrun;
  if (!__all(tmax <= mold + 8.0f)) {      // slow path: rescale
    const float mnew = fmaxf(mold, tmax);
    const float alpha = EXP2F(mold - mnew);
#pragma unroll
    for (int ni = 0; ni < 4; ++ni)
#pragma unroll
      for (int r = 0; r < 4; ++r) oacc[ni][r] *= alpha;
    lsum *= alpha;
    mrun = mnew;
  }
  const float m = mrun;

  float4 p0, p1, p2, p3;
  p0.x = EXP2F(s[0][0] - m); p0.y = EXP2F(s[0][1] - m);
  p0.z = EXP2F(s[0][2] - m); p0.w = EXP2F(s[0][3] - m);
  p1.x = EXP2F(s[1][0] - m); p1.y = EXP2F(s[1][1] - m);
  p1.z = EXP2F(s[1][2] - m); p1.w = EXP2F(s[1][3] - m);
  p2.x = EXP2F(s[2][0] - m); p2.y = EXP2F(s[2][1] - m);
  p2.z = EXP2F(s[2][2] - m); p2.w = EXP2F(s[2][3] - m);
  p3.x = EXP2F(s[3][0] - m); p3.y = EXP2F(s[3][1] - m);
  p3.z = EXP2F(s[3][2] - m); p3.w = EXP2F(s[3][3] - m);

  lsum += ((p0.x + p0.y) + (p0.z + p0.w)) + ((p1.x + p1.y) + (p1.z + p1.w))
        + ((p2.x + p2.y) + (p2.z + p2.w)) + ((p3.x + p3.y) + (p3.z + p3.w));

  pf0 = pack8(p0, p2);    // kv = quad*8 + 0..7       (PV call kk=0)
  pf1 = pack8(p1, p3);    // kv = 32 + quad*8 + 0..7  (PV call kk=1)
}

// Flash attention, causal, exp2-domain (Q pre-scaled by SCL*log2e).
// Round-11 version UNCHANGED (73.4 us, passing): Ks physical row permutation
// (phys row ni*16+m holds K row f(ni,m)), lane-local P->PV repack, 32 q-rows
// per wave (two 16-row groups sharing K/V fragment reads), grid (8,64),
// serial pairing {qt, 15-qt}, KVBLK=64, T13 defer-max, T14 named-scalar
// prefetch. Output IN-PLACE over Q. LDS 18.4 KB.
__global__ __launch_bounds__(256, 2)
void attn_kernel(__bf16* __restrict__ Q, const __bf16* __restrict__ K,
                 const __bf16* __restrict__ Vt)
{
  __shared__ __attribute__((aligned(16))) __bf16 Ks[64 * 72];      // [phys kv][d]
  __shared__ __attribute__((aligned(16))) __bf16 Vs[64 * 72];      // [d][kv]

  const int tid  = threadIdx.x;
  const int wave = tid >> 6, lane = tid & 63;
  const int l15  = lane & 15, quad = lane >> 4;
  const int qtA  = blockIdx.x, bh = blockIdx.y;   // qtA in 0..7
  const size_t hb = (size_t)bh * (S_ * 64);
  const float MASKV = -1.0e30f;

  const int srow = tid >> 3;          // 0..31
  const int scol = (tid & 7) << 3;    // 0,8,...,56
  // physical row for K permutation: row srow -> prow, row srow+32 -> prow+16
  const int prow = ((srow >> 2) & 1) * 32 + ((srow >> 3) & 3) * 4 + (srow & 3);

  for (int qsel = 0; qsel < 2; ++qsel) {
    const int qt = qsel ? (15 - qtA) : qtA;   // 128-row q-tile index
    const int qw = qt * 128 + wave * 32;      // wave's first q row
    const int myqA = qw + l15;                // group A lane q row
    const int myqB = qw + 16 + l15;           // group B lane q row
    const int nsub = 2 * qt + 2;              // 64-kv sub-tiles to stage

    // Q fragments (B-operand view Q^T[c][q=l15]), named scalars
    const __bf16* qpA = Q + hb + (size_t)myqA * 64 + quad * 8;
    const __bf16* qpB = Q + hb + (size_t)myqB * 64 + quad * 8;
    short8 aqA0 = *(const short8*)(qpA);
    short8 aqA1 = *(const short8*)(qpA + 32);
    short8 aqB0 = *(const short8*)(qpB);
    short8 aqB1 = *(const short8*)(qpB + 32);

    floatx4 oaccA[4], oaccB[4];     // O^T: d = ni*16+quad*4+r, q = l15
#pragma unroll
    for (int j = 0; j < 4; ++j) {
      oaccA[j] = (floatx4){0.f, 0.f, 0.f, 0.f};
      oaccB[j] = (floatx4){0.f, 0.f, 0.f, 0.f};
    }
    float lsumA = 0.f, lsumB = 0.f;
    float mrunA = MASKV, mrunB = MASKV;

    // prologue: issue kt=0 tile loads into NAMED scalar regs (T14 issue-early)
    uint4 kreg0, kreg1, vreg0, vreg1;
    {
      const __bf16* kp = K  + hb + (size_t)srow * 64 + scol;
      const __bf16* vp = Vt + hb + (size_t)srow * S_ + scol;
      kreg0 = *(const uint4*)kp;
      kreg1 = *(const uint4*)(kp + 32 * 64);
      vreg0 = *(const uint4*)vp;
      vreg1 = *(const uint4*)(vp + (size_t)32 * S_);
    }

    for (int kt = 0; kt < nsub; ++kt) {
      __syncthreads();                      // all waves done reading prev tile
      *(uint4*)(&Ks[prow * 72 + scol])        = kreg0;   // K row srow
      *(uint4*)(&Ks[(prow + 16) * 72 + scol]) = kreg1;   // K row srow+32
      *(uint4*)(&Vs[srow * 72 + scol])        = vreg0;
      *(uint4*)(&Vs[(srow + 32) * 72 + scol]) = vreg1;
      __syncthreads();                      // tile staged

      if (kt + 1 < nsub) {                  // prefetch next 64-kv tile
        const __bf16* kp = K  + hb + (size_t)((kt + 1) * 64 + srow) * 64 + scol;
        const __bf16* vp = Vt + hb + (size_t)srow * S_ + (kt + 1) * 64 + scol;
        kreg0 = *(const uint4*)kp;
        kreg1 = *(const uint4*)(kp + 32 * 64);
        vreg0 = *(const uint4*)vp;
        vreg1 = *(const uint4*)(vp + (size_t)32 * S_);
      }

      if (kt * 64 <= qw + 31) {             // wave-uniform compute-skip
        // S^T = K Q^T for BOTH groups; bk fragments read ONCE (linear rows,
        // permuted CONTENT: phys row ni*16+l15 holds K row f(ni,l15)).
        floatx4 sA[4], sB[4];
#pragma unroll
        for (int j = 0; j < 4; ++j) {
          sA[j] = (floatx4){0.f, 0.f, 0.f, 0.f};
          sB[j] = (floatx4){0.f, 0.f, 0.f, 0.f};
        }
#pragma unroll
        for (int kk = 0; kk < 2; ++kk) {
          const short8 aqa = kk ? aqA1 : aqA0;
          const short8 aqb = kk ? aqB1 : aqB0;
          short8 bk[4];
#pragma unroll
          for (int ni = 0; ni < 4; ++ni)
            bk[ni] = *(const short8*)(&Ks[(ni * 16 + l15) * 72 + kk * 32 + quad * 8]);
#pragma unroll
          for (int ni = 0; ni < 4; ++ni)
            sA[ni] = __builtin_amdgcn_mfma_f32_16x16x32_bf16(bk[ni], aqa, sA[ni], 0, 0, 0);
#pragma unroll
          for (int ni = 0; ni < 4; ++ni)
            sB[ni] = __builtin_amdgcn_mfma_f32_16x16x32_bf16(bk[ni], aqb, sB[ni], 0, 0, 0);
        }

        // causal masks with kv = kt*64 + (ni&1)*32 + quad*8 + (ni>>1)*4 + r
        const int kb2 = kt * 64 + quad * 8;
        if (kt * 64 + 63 > qw) {            // group A diagonal overlap
#pragma unroll
          for (int ni = 0; ni < 4; ++ni)
#pragma unroll
            for (int r = 0; r < 4; ++r) {
              const int kvg = kb2 + ((ni & 1) << 5) + ((ni >> 1) << 2) + r;
              if (kvg > myqA) sA[ni][r] = MASKV;
            }
        }
        if (kt * 64 + 63 > qw + 16) {       // group B diagonal overlap
#pragma unroll
          for (int ni = 0; ni < 4; ++ni)
#pragma unroll
            for (int r = 0; r < 4; ++r) {
              const int kvg = kb2 + ((ni & 1) << 5) + ((ni >> 1) << 2) + r;
              if (kvg > myqB) sB[ni][r] = MASKV;
            }
        }

        short8 pfA0, pfA1, pfB0, pfB1;
        softmax_update_pf(sA, mrunA, lsumA, oaccA, pfA0, pfA1);
        softmax_update_pf(sB, mrunB, lsumB, oaccB, pfB0, pfB1);

        // O^T += V^T P^T; P fragments are lane-local (no LDS, no fence).
#pragma unroll
        for (int kk = 0; kk < 2; ++kk) {
          short8 bv[4];
#pragma unroll
          for (int ni = 0; ni < 4; ++ni)
            bv[ni] = *(const short8*)(&Vs[(ni * 16 + l15) * 72 + kk * 32 + quad * 8]);
          const short8 pfA = kk ? pfA1 : pfA0;
          const short8 pfB = kk ? pfB1 : pfB0;
#pragma unroll
          for (int ni = 0; ni < 4; ++ni)
            oaccA[ni] = __builtin_amdgcn_mfma_f32_16x16x32_bf16(bv[ni], pfA, oaccA[ni], 0, 0, 0);
#pragma unroll
          for (int ni = 0; ni < 4; ++ni)
            oaccB[ni] = __builtin_amdgcn_mfma_f32_16x16x32_bf16(bv[ni], pfB, oaccB[ni], 0, 0, 0);
        }
      }
    }

    // epilogues: l(q) = sum over 4 quads of lane-local partials
    {
      float l = lsumA;
      l += __shfl_xor(l, 16);
      l += __shfl_xor(l, 32);
      const float inv = 1.0f / fmaxf(l, 1e-20f);
      const size_t rowb = hb + (size_t)myqA * 64;
#pragma unroll
      for (int ni = 0; ni < 4; ++ni) {
        float4 o;
        o.x = oaccA[ni][0] * inv;
        o.y = oaccA[ni][1] * inv;
        o.z = oaccA[ni][2] * inv;
        o.w = oaccA[ni][3] * inv;
        *(ushort4*)(Q + rowb + ni * 16 + quad * 4) = cvt4(o);  // 8B aligned
      }
    }
    {
      float l = lsumB;
      l += __shfl_xor(l, 16);
      l += __shfl_xor(l, 32);
      const float inv = 1.0f / fmaxf(l, 1e-20f);
      const size_t rowb = hb + (size_t)myqB * 64;
#pragma unroll
      for (int ni = 0; ni < 4; ++ni) {
        float4 o;
        o.x = oaccB[ni][0] * inv;
        o.y = oaccB[ni][1] * inv;
        o.z = oaccB[ni][2] * inv;
        o.w = oaccB[ni][3] * inv;
        *(ushort4*)(Q + rowb + ni * 16 + quad * 4) = cvt4(o);  // 8B aligned
      }
    }
  }
}

// Final projection: A = attn output (bf16, BHSD gather), W = Wob bf16,
// bias fp32, out fp32 row-major. Same T3 2-phase double-buffer as gemm_qkv;
// same bank-conflict swizzle (round 11).
__global__ __launch_bounds__(256)
void gemm_o_kernel(const __bf16* __restrict__ A, const __bf16* __restrict__ W,
                   const float* __restrict__ bias, float* __restrict__ out)
{
  __shared__ __attribute__((aligned(16))) __bf16 As0[128 * 32];
  __shared__ __attribute__((aligned(16))) __bf16 Ws0[128 * 32];
  __shared__ __attribute__((aligned(16))) __bf16 As1[128 * 32];
  __shared__ __attribute__((aligned(16))) __bf16 Ws1[128 * 32];
  const int tid  = threadIdx.x;
  const int wave = tid >> 6, lane = tid & 63;
  const int l15  = lane & 15, quad = lane >> 4;
  const int wm   = wave >> 1, wn = wave & 1;
  const int bm   = blockIdx.y * 128;
  const int bn   = blockIdx.x * 128;

  floatx4 acc[4][4];
#pragma unroll
  for (int i = 0; i < 4; ++i)
#pragma unroll
    for (int j = 0; j < 4; ++j) acc[i][j] = (floatx4){0.f, 0.f, 0.f, 0.f};

  const int srow = tid >> 2;
  const int gcol = (((tid & 3) ^ ((tid >> 3) & 3)) << 3);   // swizzled global col
  const int xsw  = (l15 >> 1) & 3;                          // read-side swizzle
  const __bf16* Wg = W + (size_t)(bn + srow) * 1024 + gcol;
  const int bb = bm >> 11;                 // batch
  const int ss = (bm & 2047) + srow;       // seq
  const int d8 = tid * 8;

  auto stage = [&](__bf16* bA, __bf16* bW, int kk) {
    const int c = kk + gcol, h = c >> 6, dd = c & 63;  // 8-chunks never cross a head
    const __bf16* pa0 = A + (((size_t)(bb * 16 + h) * S_) + ss) * 64 + dd;
    async_cp16(pa0,           bA + d8);
    async_cp16(pa0 + 64 * 64, bA + d8 + 2048);         // s -> s+64
    async_cp16(Wg + kk,             bW + d8);
    async_cp16(Wg + kk + 64 * 1024, bW + d8 + 2048);
  };
  auto compute = [&](const __bf16* bA, const __bf16* bW) {
    short8 af[4], wf[4];
#pragma unroll
    for (int mi = 0; mi < 4; ++mi)
      af[mi] = *(const short8*)(bA + ((wm * 64 + mi * 16 + l15) << 5) + ((quad ^ xsw) << 3));
#pragma unroll
    for (int ni = 0; ni < 4; ++ni)
      wf[ni] = *(const short8*)(bW + ((wn * 64 + ni * 16 + l15) << 5) + ((quad ^ xsw) << 3));
#pragma unroll
    for (int mi = 0; mi < 4; ++mi)
#pragma unroll
      for (int ni = 0; ni < 4; ++ni)
        acc[mi][ni] = __builtin_amdgcn_mfma_f32_16x16x32_bf16(af[mi], wf[ni], acc[mi][ni], 0, 0, 0);
  };

  stage(As0, Ws0, 0);
  __syncthreads();
  for (int k0 = 0; k0 < 1024; k0 += 64) {
    stage(As1, Ws1, k0 + 32);
    compute(As0, Ws0);
    __syncthreads();
    if (k0 + 64 < 1024) stage(As0, Ws0, k0 + 64);
    compute(As1, Ws1);
    __syncthreads();
  }

#pragma unroll
  for (int ni = 0; ni < 4; ++ni) {
    const int n = bn + wn * 64 + ni * 16 + l15;
    const float bvb = bias[n];
#pragma unroll
    for (int mi = 0; mi < 4; ++mi) {
      const int m0 = bm + wm * 64 + mi * 16 + quad * 4;
      floatx4 v = acc[mi][ni];
#pragma unroll
      for (int r = 0; r < 4; ++r)
        out[(size_t)(m0 + r) * 1024 + n] = v[r] + bvb;
    }
  }
}

extern "C" void kernel_launch(void* const* d_in, const int* in_sizes, int n_in,
                              void* d_out, int out_size, void* d_ws, size_t ws_size,
                              hipStream_t stream) {
  const float* x  = (const float*)d_in[0];
  const float* Wq = (const float*)d_in[1];
  const float* bq = (const float*)d_in[2];
  const float* Wk = (const float*)d_in[3];
  const float* bk = (const float*)d_in[4];
  const float* Wv = (const float*)d_in[5];
  const float* bv = (const float*)d_in[6];
  const float* Wo = (const float*)d_in[7];
  const float* bo = (const float*)d_in[8];
  // d_in[9] = causal_mask (int32) — causality implemented analytically, unused.

  const size_t BUF = (size_t)B_ * NH_ * S_ * HD_;   // 8388608 elems
  __bf16* ws   = (__bf16*)d_ws;                     // ws usage: ~42 MB
  __bf16* xb   = ws;                                // 8388608  (16.8 MB)
  __bf16* Wcat = ws + 8388608;                      // 3145728  (6 MB)
  __bf16* Wob  = ws + 11534336;                     // 1048576  (2 MB)
  __bf16* Qb   = ws + 12582912;                     // 8388608  (16.8 MB)
  float*  bcat = (float*)(ws + 20971520);           // 3072 fp32 (12 KB)
  __bf16* Kb   = (__bf16*)d_out;                    // d_out reused as K+V^T
  __bf16* Vb   = (__bf16*)d_out + BUF;              // scratch until attn done

  dim3 blk(256);
  cvt_kernel<<<12291, blk, 0, stream>>>(x, Wq, Wk, Wv, Wo, bq, bk, bv,
                                        xb, Wcat, Wob, bcat);
  gemm_qkv_kernel<<<dim3(24, 64), blk, 0, stream>>>(xb, Wcat, bcat, Qb, Kb, Vb);
  attn_kernel<<<dim3(8, 64), blk, 0, stream>>>(Qb, Kb, Vb);
  gemm_o_kernel<<<dim3(8, 64), blk, 0, stream>>>(Qb, Wob, bo, (float*)d_out);
}